// Round 9
// baseline (101.105 us; speedup 1.0000x reference)
//
#include <hip/hip_runtime.h>
#include <math.h>

#define EPSF 1e-8f

// ws float layout:
// [0..15]  cnt per b (float)
// [16] score_num  [17] score_cnt
// [18] gb_sum  [19] gi_sum  [20] gpa_sum   (filled by finalize)
// [21] match1  [22] match2  [23] pose1  [24] pose2  [25] gpo
// [32 ..]  pacc[half][pr][b][q][4096]  (2 c-halves, 3 pairs, q = dot/|a|^2/|b|^2)
//          = 4.72 MB, written with PLAIN stores (disjoint per block), no atomics

#define PACC_OFF   32
#define PACC_FLTS  (2 * 3 * 16 * 3 * 4096)

#define FEAT_BLOCKS  1024  // 16 b * 32 n-chunks * 2 c-halves
#define SCORE_BLOCKS 512
#define SMALL_BLOCKS 256
#define MEGA_BLOCKS  (FEAT_BLOCKS + SCORE_BLOCKS + SMALL_BLOCKS)

__device__ __forceinline__ float blockReduceSum(float v, float* sbuf) {
    int lane = threadIdx.x & 63;
    int wid  = threadIdx.x >> 6;
    #pragma unroll
    for (int o = 32; o > 0; o >>= 1) v += __shfl_down(v, o, 64);
    if (lane == 0) sbuf[wid] = v;
    __syncthreads();
    int nw = (blockDim.x + 63) >> 6;
    v = (wid == 0 && lane < nw) ? sbuf[lane] : 0.0f;
    if (wid == 0) {
        #pragma unroll
        for (int o = 32; o > 0; o >>= 1) v += __shfl_down(v, o, 64);
    }
    __syncthreads();
    return v;          // valid in thread 0
}

__device__ __forceinline__ void fma4(float4& a, const float4 x, const float4 y) {
    a.x += x.x * y.x; a.y += x.y * y.y; a.z += x.z * y.z; a.w += x.w * y.w;
}
__device__ __forceinline__ float getc(const float4 v, int c) {
    return c == 0 ? v.x : (c == 1 ? v.y : (c == 2 ? v.z : v.w));
}

// ---------------- K1: relation -> cnt[b] (float counts in ws[0..15]) --------
__global__ void cnt_kernel(const float* __restrict__ rel, float* __restrict__ cntf) {
    int i = blockIdx.x * 256 + threadIdx.x;         // 65536 = 16*4096
    float4 r = ((const float4*)rel)[i];             // relation[...,1,:] -> z,w
    float c = (r.z > 0.0f && r.w > 0.0f) ? 1.0f : 0.0f;
    __shared__ float sbuf[16];
    float tot = blockReduceSum(c, sbuf);
    if (threadIdx.x == 0) atomicAdd(&cntf[i >> 12], tot);  // b constant per block
}

// ---------------- K2: mega kernel (feat + score + small roles) --------------
__global__ __launch_bounds__(256)
void mega_kernel(const float* __restrict__ f0, const float* __restrict__ f1,
                 const float* __restrict__ f2, const float* __restrict__ f3,
                 const float* __restrict__ f4, const float* __restrict__ f5,
                 const float* __restrict__ score, const float* __restrict__ label,
                 const float* __restrict__ kp,   const float* __restrict__ pose,
                 const float* __restrict__ t1,   const float* __restrict__ proj1,
                 const float* __restrict__ t2,   const float* __restrict__ proj2,
                 const float* __restrict__ kgen, float* __restrict__ acc) {
    __shared__ float4 sd4[3][8][32];   // one pair per pass (12.3 KB)
    __shared__ float  rbuf[16];
    const int blk = blockIdx.x;
    const int t   = threadIdx.x;

    if (blk < FEAT_BLOCKS) {
        // ---- feature partials (dead-column skip; plain-store epilogue) ----
        const int b     = blk >> 6;          // 16
        const int rem   = blk & 63;
        const int chunk = rem >> 1;          // 32 n-chunks of 128 n
        const int half  = rem & 1;           // c rows [half*128, half*128+128)
        const int nl    = t & 31;            // float4 lane along n
        const int cq    = t >> 5;            // 0..7 c-group (16 rows each)
        const int n4    = chunk * 32 + nl;   // float4-col id in [0,1024)

        const bool full = (chunk * 128) < (int)acc[b];   // need pairs 0/1?

        const float4* A[3]  = {(const float4*)f0, (const float4*)f2, (const float4*)f4};
        const float4* Bp[3] = {(const float4*)f1, (const float4*)f3, (const float4*)f5};
        unsigned base = ((unsigned)(b * 256 + half * 128 + cq * 16)) * 1024u
                      + (unsigned)n4;

        float4 dd[3] = {{0,0,0,0},{0,0,0,0},{0,0,0,0}};
        float4 sa[3] = {{0,0,0,0},{0,0,0,0},{0,0,0,0}};
        float4 sb[3] = {{0,0,0,0},{0,0,0,0},{0,0,0,0}};
        if (full) {
            #pragma unroll 2
            for (int c = 0; c < 16; c++) {
                unsigned idx = base + (unsigned)c * 1024u;
                float4 av[3], bv[3];
                #pragma unroll
                for (int p = 0; p < 3; p++) { av[p] = A[p][idx]; bv[p] = Bp[p][idx]; }
                #pragma unroll
                for (int p = 0; p < 3; p++) {
                    fma4(dd[p], av[p], bv[p]);
                    fma4(sa[p], av[p], av[p]);
                    fma4(sb[p], bv[p], bv[p]);
                }
            }
        } else {
            #pragma unroll 4
            for (int c = 0; c < 16; c++) {
                unsigned idx = base + (unsigned)c * 1024u;
                float4 av = A[2][idx], bv = Bp[2][idx];
                fma4(dd[2], av, bv);
                fma4(sa[2], av, av);
                fma4(sb[2], bv, bv);
            }
        }

        const int p0 = full ? 0 : 2;
        for (int p = p0; p < 3; p++) {       // one pair per pass, plain stores
            sd4[0][cq][nl] = dd[p];
            sd4[1][cq][nl] = sa[p];
            sd4[2][cq][nl] = sb[p];
            __syncthreads();
            if (cq == 0) {
                #pragma unroll
                for (int qi = 0; qi < 3; qi++) {
                    float4 s = sd4[qi][0][nl];
                    #pragma unroll
                    for (int k = 1; k < 8; k++) {
                        float4 x = sd4[qi][k][nl];
                        s.x += x.x; s.y += x.y; s.z += x.z; s.w += x.w;
                    }
                    // disjoint slice: [half][p][b][qi][n4*4 ..]
                    float4* dst = (float4*)(acc + PACC_OFF
                        + (size_t)((((half * 3 + p) * 16 + b) * 3 + qi)) * 4096) + n4;
                    *dst = s;
                }
            }
            __syncthreads();
        }

    } else if (blk < FEAT_BLOCKS + SCORE_BLOCKS) {
        // ---- score loss (34 MB stream), 16 loads hoisted ----
        const int sb_ = blk - FEAT_BLOCKS;
        const int TOT4 = (8 * 512 * 512) / 4;      // 524288 float4 slots
        const float4* S = (const float4*)score;
        const float4* L = (const float4*)label;
        const int j0 = sb_ * 256 + t;
        float4 S0[4], S1[4], LA[4], LB[4];
        #pragma unroll
        for (int it = 0; it < 4; it++) {
            int j = j0 + it * (SCORE_BLOCKS * 256);
            S0[it] = S[j];
            S1[it] = S[TOT4 + j];
            LA[it] = L[2 * j];
            LB[it] = L[2 * j + 1];
        }
        float num = 0.0f, cntv = 0.0f;
        #pragma unroll
        for (int it = 0; it < 4; it++) {
            float4 s0 = S0[it], s1 = S1[it], la = LA[it], lb = LB[it];
            if (s0.x > 1e-8f) { float d = s0.x - la.x; num += d*d; cntv += 1.0f; }
            if (s1.x > 1e-8f) { float d = s1.x - la.y; num += d*d; cntv += 1.0f; }
            if (s0.y > 1e-8f) { float d = s0.y - la.z; num += d*d; cntv += 1.0f; }
            if (s1.y > 1e-8f) { float d = s1.y - la.w; num += d*d; cntv += 1.0f; }
            if (s0.z > 1e-8f) { float d = s0.z - lb.x; num += d*d; cntv += 1.0f; }
            if (s1.z > 1e-8f) { float d = s1.z - lb.y; num += d*d; cntv += 1.0f; }
            if (s0.w > 1e-8f) { float d = s0.w - lb.z; num += d*d; cntv += 1.0f; }
            if (s1.w > 1e-8f) { float d = s1.w - lb.w; num += d*d; cntv += 1.0f; }
        }
        float r;
        r = blockReduceSum(num,  rbuf); if (t == 0) atomicAdd(&acc[16], r);
        r = blockReduceSum(cntv, rbuf); if (t == 0) atomicAdd(&acc[17], r);

    } else {
        // ---- sinkhorn / pose / gen_points (~7 MB) ----
        const int i = (blk - FEAT_BLOCKS - SCORE_BLOCKS) * 256 + t;  // 0..65535
        const int b = i >> 12;
        const int n = i & 4095;

        float m1 = 0, m2 = 0, p1 = 0, p2 = 0, g = 0;
        float4 k = ((const float4*)kp)[i];

        if (b < 8) {
            const float* P  = pose + b * 16;
            const float* T1 = t1 + b * 16;
            const float* T2 = t2 + b * 16;
            float ssq1 = 0, ssq2 = 0;
            #pragma unroll
            for (int r = 0; r < 3; r++) {
                float base3 = P[r*4+0]*k.x + P[r*4+1]*k.y + P[r*4+2]*k.z;
                float g1 = base3 + P[r*4+3];          // w = 1 (sinkhorn)
                float gw = base3 + P[r*4+3]*k.w;      // w = k.w (pose loss)
                float q1 = proj1[i*3 + r];
                float q2 = proj2[i*3 + r];
                float d1 = g1 - q1, d2 = g1 - q2;
                ssq1 += d1 * d1; ssq2 += d2 * d2;
                float pa = T1[r*4+0]*k.x + T1[r*4+1]*k.y + T1[r*4+2]*k.z + T1[r*4+3]*k.w;
                float pb = T2[r*4+0]*k.x + T2[r*4+1]*k.y + T2[r*4+2]*k.z + T2[r*4+3]*k.w;
                p1 += fabsf(pa - gw);
                p2 += fabsf(pb - gw);
            }
            m1 = sqrtf(ssq1);
            m2 = sqrtf(ssq2);
            float s0 = P[0]*k.x + P[1]*k.y + P[2]*k.z + P[3]*k.w;
            float s1 = P[4]*k.x + P[5]*k.y + P[6]*k.z + P[7]*k.w;
            float2 tg = ((const float2*)kgen)[(8 + b) * 4096 + n];
            g = fabsf(s0 - tg.x) + fabsf(s1 - tg.y);
        } else {
            int j = b - 8;
            const float* P = pose + j * 16;
            float2 kg = ((const float2*)kgen)[j * 4096 + n];
            float s0 = P[0]*kg.x + P[1]*kg.y + P[3];
            float s1 = P[4]*kg.x + P[5]*kg.y + P[7];
            g = fabsf(s0 - k.x) + fabsf(s1 - k.y);
        }
        float r;
        r = blockReduceSum(m1, rbuf); if (t == 0) atomicAdd(&acc[21], r);
        r = blockReduceSum(m2, rbuf); if (t == 0) atomicAdd(&acc[22], r);
        r = blockReduceSum(p1, rbuf); if (t == 0) atomicAdd(&acc[23], r);
        r = blockReduceSum(p2, rbuf); if (t == 0) atomicAdd(&acc[24], r);
        r = blockReduceSum(g,  rbuf); if (t == 0) atomicAdd(&acc[25], r);
    }
}

// ---------------- K3: finalize feature cosines from pacc --------------------
__global__ void finalize_kernel(float* __restrict__ ws) {
    // grid: 48 blocks = (pr,b); 256 threads; reads 4.72 MB (L2/L3-resident)
    const int blk = blockIdx.x;
    const int pr  = blk >> 4;
    const int b   = blk & 15;
    const int t   = threadIdx.x;
    const float4* H0 = (const float4*)(ws + PACC_OFF
                     + (size_t)(((0 * 3 + pr) * 16 + b) * 3) * 4096);
    const float4* H1 = (const float4*)(ws + PACC_OFF
                     + (size_t)(((1 * 3 + pr) * 16 + b) * 3) * 4096);
    const float cb    = ws[b];
    const float denom = fmaxf(cb, 1.0f);
    const int   cbi   = (int)cb;

    float v = 0.0f;
    #pragma unroll
    for (int it = 0; it < 4; it++) {
        int n4 = t + it * 256;
        float4 d, sa, sb;
        {
            float4 x = H0[0 * 1024 + n4], y = H1[0 * 1024 + n4];
            d  = {x.x + y.x, x.y + y.y, x.z + y.z, x.w + y.w};
            x = H0[1 * 1024 + n4]; y = H1[1 * 1024 + n4];
            sa = {x.x + y.x, x.y + y.y, x.z + y.z, x.w + y.w};
            x = H0[2 * 1024 + n4]; y = H1[2 * 1024 + n4];
            sb = {x.x + y.x, x.y + y.y, x.z + y.z, x.w + y.w};
        }
        #pragma unroll
        for (int comp = 0; comp < 4; comp++) {
            float c = 1.0f - getc(d, comp) /
                      fmaxf(sqrtf(getc(sa, comp)) * sqrtf(getc(sb, comp)), EPSF);
            int n = n4 * 4 + comp;
            if (pr == 2)      v += c;
            else if (n < cbi) v += c / denom;
        }
    }
    __shared__ float rbuf[16];
    float r = blockReduceSum(v, rbuf);
    if (t == 0) atomicAdd(&ws[18 + pr], r);
}

// ---------------- K4: tr losses + final combine ----------------
__global__ void combine_kernel(const float* __restrict__ pose,
                               const float* __restrict__ t1,
                               const float* __restrict__ t2,
                               const float* __restrict__ ws,
                               float* __restrict__ out) {
    int t = threadIdx.x;   // 64
    float dt1 = 0, dt2 = 0, r1 = 0, r2 = 0;
    if (t < 8) {
        float ap = acosf(fminf(fmaxf(pose[t*16], -1.0f), 1.0f));
        float a1 = acosf(fminf(fmaxf(t1[t*16],   -1.0f), 1.0f));
        float a2 = acosf(fminf(fmaxf(t2[t*16],   -1.0f), 1.0f));
        r1 = fabsf(a1 - ap);
        r2 = fabsf(a2 - ap);
        float s1 = 0, s2 = 0;
        #pragma unroll
        for (int r = 0; r < 3; r++) {
            float pv = pose[t*16 + r*4 + 3];
            float d1 = t1[t*16 + r*4 + 3] - pv;
            float d2 = t2[t*16 + r*4 + 3] - pv;
            s1 += d1 * d1;
            s2 += d2 * d2;
        }
        dt1 = sqrtf(s1);
        dt2 = sqrtf(s2);
    }
    #pragma unroll
    for (int o = 4; o > 0; o >>= 1) {
        dt1 += __shfl_down(dt1, o, 64);
        dt2 += __shfl_down(dt2, o, 64);
        r1  += __shfl_down(r1,  o, 64);
        r2  += __shfl_down(r2,  o, 64);
    }
    if (t == 0) {
        float l_tra1 = dt1 / 8.0f;
        float l_tra2 = dt2 / 8.0f;
        float l_rot1 = (r1 / 8.0f) / 3.1415f * 180.0f;
        float l_rot2 = (r2 / 8.0f) / 3.1415f * 180.0f;
        float cnt = (fminf(l_rot1, l_rot2) > 0.0f) ? 2.0f : 1.0f;

        float l_score = ws[16] / fmaxf(ws[17], 1.0f);
        float l_match = (ws[21] + ws[22]) / 32768.0f / cnt;
        float l_pose  = (ws[23] + ws[24]) / 98304.0f / cnt;
        float l_tra   = (l_tra1 + l_tra2) / cnt;
        float l_rot   = (l_rot1 + l_rot2) / cnt;
        float l_gb    = ws[18] / 16.0f;
        float l_gi    = ws[19] / 16.0f;
        float l_gpa   = ws[20] / 65536.0f;
        float l_gpo   = ws[25] / 131072.0f;

        out[0] = l_pose + l_score + l_match + l_tra + l_rot
               + l_gb + l_gi + l_gpa + l_gpo;
    }
}

extern "C" void kernel_launch(void* const* d_in, const int* in_sizes, int n_in,
                              void* d_out, int out_size, void* d_ws, size_t ws_size,
                              hipStream_t stream) {
    const float* score_bev   = (const float*)d_in[0];
    const float* label_score = (const float*)d_in[1];
    const float* key_points  = (const float*)d_in[2];
    const float* pose        = (const float*)d_in[3];
    // d_in[4] = batch_size (scalar, fixed = 16)
    const float* t_orig      = (const float*)d_in[5];
    const float* proj_orig   = (const float*)d_in[6];
    const float* t_fus       = (const float*)d_in[7];
    const float* proj_fus    = (const float*)d_in[8];
    const float* f_pt        = (const float*)d_in[9];
    const float* f_pt_g      = (const float*)d_in[10];
    const float* f_pl        = (const float*)d_in[11];
    const float* f_pl_g      = (const float*)d_in[12];
    const float* f_kpt       = (const float*)d_in[13];
    const float* f_kpt_g     = (const float*)d_in[14];
    const float* relation    = (const float*)d_in[15];
    const float* kgen        = (const float*)d_in[16];

    float* ws  = (float*)d_ws;
    float* out = (float*)d_out;

    hipMemsetAsync(d_ws, 0, (PACC_OFF + PACC_FLTS) * sizeof(float), stream);

    cnt_kernel<<<256, 256, 0, stream>>>(relation, ws);
    mega_kernel<<<MEGA_BLOCKS, 256, 0, stream>>>(
        f_pt, f_pt_g, f_pl, f_pl_g, f_kpt, f_kpt_g,
        score_bev, label_score,
        key_points, pose, t_orig, proj_orig, t_fus, proj_fus, kgen, ws);
    finalize_kernel<<<48, 256, 0, stream>>>(ws);
    combine_kernel<<<1, 64, 0, stream>>>(pose, t_orig, t_fus, ws, out);
}

// Round 10
// 88.238 us; speedup vs baseline: 1.1458x; 1.1458x over previous
//
#include <hip/hip_runtime.h>
#include <math.h>

#define EPSF 1e-8f

// ws float layout:
// [0..15]  cnt per b (float)
// [16] score_num  [17] score_cnt
// [18] gb_sum  [19] gi_sum  [20] gpa_sum   (atomic, filled by final_kernel blocks 0-47)
// [21] match1  [22] match2  [23] pose1  [24] pose2  [25] gpo
// [27] arrival counter (as uint)   [28..31] dt1/dt2/r1/r2 (atomic comm slots)
// [32 ..]  pacc[pr][b][q][4096]  (pr=3 pairs, q = dot/|a|^2/|b|^2) = 2.36 MB

#define PACC_OFF   32
#define PACC_FLTS  (3 * 16 * 3 * 4096)

#define FEAT_BLOCKS  1024  // 16 b * 32 n-chunks * 2 c-halves (6 streams each)
#define SCORE_BLOCKS 512
#define SMALL_BLOCKS 256
#define MEGA_BLOCKS  (FEAT_BLOCKS + SCORE_BLOCKS + SMALL_BLOCKS)

__device__ __forceinline__ float blockReduceSum(float v, float* sbuf) {
    int lane = threadIdx.x & 63;
    int wid  = threadIdx.x >> 6;
    #pragma unroll
    for (int o = 32; o > 0; o >>= 1) v += __shfl_down(v, o, 64);
    if (lane == 0) sbuf[wid] = v;
    __syncthreads();
    int nw = (blockDim.x + 63) >> 6;
    v = (wid == 0 && lane < nw) ? sbuf[lane] : 0.0f;
    if (wid == 0) {
        #pragma unroll
        for (int o = 32; o > 0; o >>= 1) v += __shfl_down(v, o, 64);
    }
    __syncthreads();
    return v;          // valid in thread 0
}

__device__ __forceinline__ void fma4(float4& a, const float4 x, const float4 y) {
    a.x += x.x * y.x; a.y += x.y * y.y; a.z += x.z * y.z; a.w += x.w * y.w;
}
__device__ __forceinline__ float getc(const float4 v, int c) {
    return c == 0 ? v.x : (c == 1 ? v.y : (c == 2 ? v.z : v.w));
}

// ---------------- K1: relation -> cnt[b] (float counts in ws[0..15]) --------
__global__ void cnt_kernel(const float* __restrict__ rel, float* __restrict__ cntf) {
    int i = blockIdx.x * 256 + threadIdx.x;         // 65536 = 16*4096
    float4 r = ((const float4*)rel)[i];             // relation[...,1,:] -> z,w
    float c = (r.z > 0.0f && r.w > 0.0f) ? 1.0f : 0.0f;
    __shared__ float sbuf[16];
    float tot = blockReduceSum(c, sbuf);
    if (threadIdx.x == 0) atomicAdd(&cntf[i >> 12], tot);  // b constant per block
}

// ---------------- K2: mega kernel (feat + score + small roles) --------------
// EXACT R7 structure (the proven 89.9 us configuration).
__global__ __launch_bounds__(256)
void mega_kernel(const float* __restrict__ f0, const float* __restrict__ f1,
                 const float* __restrict__ f2, const float* __restrict__ f3,
                 const float* __restrict__ f4, const float* __restrict__ f5,
                 const float* __restrict__ score, const float* __restrict__ label,
                 const float* __restrict__ kp,   const float* __restrict__ pose,
                 const float* __restrict__ t1,   const float* __restrict__ proj1,
                 const float* __restrict__ t2,   const float* __restrict__ proj2,
                 const float* __restrict__ kgen, float* __restrict__ acc) {
    __shared__ float4 sd4[9][8][32];   // 9 qty x 8 c-groups x 32 n4 (36.9 KB)
    __shared__ float  rbuf[16];
    const int blk = blockIdx.x;
    const int t   = threadIdx.x;

    if (blk < FEAT_BLOCKS) {
        // ---- feature partials (dead-column skip) ----
        const int b     = blk >> 6;          // 16
        const int rem   = blk & 63;
        const int chunk = rem >> 1;          // 32 n-chunks of 128 n
        const int half  = rem & 1;           // c rows [half*128, half*128+128)
        const int nl    = t & 31;            // float4 lane along n
        const int cq    = t >> 5;            // 0..7 c-group (16 rows each)
        const int n4    = chunk * 32 + nl;   // float4-col id in [0,1024)

        const bool full = (chunk * 128) < (int)acc[b];   // need pairs 0/1?

        const float4* A[3]  = {(const float4*)f0, (const float4*)f2, (const float4*)f4};
        const float4* Bp[3] = {(const float4*)f1, (const float4*)f3, (const float4*)f5};
        unsigned base = ((unsigned)(b * 256 + half * 128 + cq * 16)) * 1024u + (unsigned)n4;

        float4 dd[3] = {{0,0,0,0},{0,0,0,0},{0,0,0,0}};
        float4 sa[3] = {{0,0,0,0},{0,0,0,0},{0,0,0,0}};
        float4 sb[3] = {{0,0,0,0},{0,0,0,0},{0,0,0,0}};
        if (full) {
            #pragma unroll 2
            for (int c = 0; c < 16; c++) {
                unsigned idx = base + (unsigned)c * 1024u;
                float4 av[3], bv[3];
                #pragma unroll
                for (int p = 0; p < 3; p++) { av[p] = A[p][idx]; bv[p] = Bp[p][idx]; }
                #pragma unroll
                for (int p = 0; p < 3; p++) {
                    fma4(dd[p], av[p], bv[p]);
                    fma4(sa[p], av[p], av[p]);
                    fma4(sb[p], bv[p], bv[p]);
                }
            }
        } else {
            #pragma unroll 4
            for (int c = 0; c < 16; c++) {
                unsigned idx = base + (unsigned)c * 1024u;
                float4 av = A[2][idx], bv = Bp[2][idx];
                fma4(dd[2], av, bv);
                fma4(sa[2], av, av);
                fma4(sb[2], bv, bv);
            }
        }

        const int p0 = full ? 0 : 2;
        #pragma unroll
        for (int p = 0; p < 3; p++) {
            if (p >= p0) {
                sd4[p*3+0][cq][nl] = dd[p];
                sd4[p*3+1][cq][nl] = sa[p];
                sd4[p*3+2][cq][nl] = sb[p];
            }
        }
        __syncthreads();

        if (cq == 0) {
            #pragma unroll
            for (int qi = 0; qi < 9; qi++) {
                if (qi >= p0 * 3) {
                    float4 s = sd4[qi][0][nl];
                    #pragma unroll
                    for (int k = 1; k < 8; k++) {
                        float4 x = sd4[qi][k][nl];
                        s.x += x.x; s.y += x.y; s.z += x.z; s.w += x.w;
                    }
                    const int p = qi / 3, qty = qi % 3;
                    float* dst = acc + PACC_OFF
                               + (size_t)((p * 16 + b) * 3 + qty) * 4096 + n4 * 4;
                    atomicAdd(&dst[0], s.x); atomicAdd(&dst[1], s.y);
                    atomicAdd(&dst[2], s.z); atomicAdd(&dst[3], s.w);
                }
            }
        }

    } else if (blk < FEAT_BLOCKS + SCORE_BLOCKS) {
        // ---- score loss (34 MB stream), 16 loads hoisted ----
        const int sb_ = blk - FEAT_BLOCKS;
        const int TOT4 = (8 * 512 * 512) / 4;      // 524288 float4 slots
        const float4* S = (const float4*)score;
        const float4* L = (const float4*)label;
        const int j0 = sb_ * 256 + t;
        float4 S0[4], S1[4], LA[4], LB[4];
        #pragma unroll
        for (int it = 0; it < 4; it++) {
            int j = j0 + it * (SCORE_BLOCKS * 256);
            S0[it] = S[j];
            S1[it] = S[TOT4 + j];
            LA[it] = L[2 * j];
            LB[it] = L[2 * j + 1];
        }
        float num = 0.0f, cntv = 0.0f;
        #pragma unroll
        for (int it = 0; it < 4; it++) {
            float4 s0 = S0[it], s1 = S1[it], la = LA[it], lb = LB[it];
            if (s0.x > 1e-8f) { float d = s0.x - la.x; num += d*d; cntv += 1.0f; }
            if (s1.x > 1e-8f) { float d = s1.x - la.y; num += d*d; cntv += 1.0f; }
            if (s0.y > 1e-8f) { float d = s0.y - la.z; num += d*d; cntv += 1.0f; }
            if (s1.y > 1e-8f) { float d = s1.y - la.w; num += d*d; cntv += 1.0f; }
            if (s0.z > 1e-8f) { float d = s0.z - lb.x; num += d*d; cntv += 1.0f; }
            if (s1.z > 1e-8f) { float d = s1.z - lb.y; num += d*d; cntv += 1.0f; }
            if (s0.w > 1e-8f) { float d = s0.w - lb.z; num += d*d; cntv += 1.0f; }
            if (s1.w > 1e-8f) { float d = s1.w - lb.w; num += d*d; cntv += 1.0f; }
        }
        float r;
        r = blockReduceSum(num,  rbuf); if (t == 0) atomicAdd(&acc[16], r);
        r = blockReduceSum(cntv, rbuf); if (t == 0) atomicAdd(&acc[17], r);

    } else {
        // ---- sinkhorn / pose / gen_points (~7 MB) ----
        const int i = (blk - FEAT_BLOCKS - SCORE_BLOCKS) * 256 + t;  // 0..65535
        const int b = i >> 12;
        const int n = i & 4095;

        float m1 = 0, m2 = 0, p1 = 0, p2 = 0, g = 0;
        float4 k = ((const float4*)kp)[i];

        if (b < 8) {
            const float* P  = pose + b * 16;
            const float* T1 = t1 + b * 16;
            const float* T2 = t2 + b * 16;
            float ssq1 = 0, ssq2 = 0;
            #pragma unroll
            for (int r = 0; r < 3; r++) {
                float base3 = P[r*4+0]*k.x + P[r*4+1]*k.y + P[r*4+2]*k.z;
                float g1 = base3 + P[r*4+3];          // w = 1 (sinkhorn)
                float gw = base3 + P[r*4+3]*k.w;      // w = k.w (pose loss)
                float q1 = proj1[i*3 + r];
                float q2 = proj2[i*3 + r];
                float d1 = g1 - q1, d2 = g1 - q2;
                ssq1 += d1 * d1; ssq2 += d2 * d2;
                float pa = T1[r*4+0]*k.x + T1[r*4+1]*k.y + T1[r*4+2]*k.z + T1[r*4+3]*k.w;
                float pb = T2[r*4+0]*k.x + T2[r*4+1]*k.y + T2[r*4+2]*k.z + T2[r*4+3]*k.w;
                p1 += fabsf(pa - gw);
                p2 += fabsf(pb - gw);
            }
            m1 = sqrtf(ssq1);
            m2 = sqrtf(ssq2);
            float s0 = P[0]*k.x + P[1]*k.y + P[2]*k.z + P[3]*k.w;
            float s1 = P[4]*k.x + P[5]*k.y + P[6]*k.z + P[7]*k.w;
            float2 tg = ((const float2*)kgen)[(8 + b) * 4096 + n];
            g = fabsf(s0 - tg.x) + fabsf(s1 - tg.y);
        } else {
            int j = b - 8;
            const float* P = pose + j * 16;
            float2 kg = ((const float2*)kgen)[j * 4096 + n];
            float s0 = P[0]*kg.x + P[1]*kg.y + P[3];
            float s1 = P[4]*kg.x + P[5]*kg.y + P[7];
            g = fabsf(s0 - k.x) + fabsf(s1 - k.y);
        }
        float r;
        r = blockReduceSum(m1, rbuf); if (t == 0) atomicAdd(&acc[21], r);
        r = blockReduceSum(m2, rbuf); if (t == 0) atomicAdd(&acc[22], r);
        r = blockReduceSum(p1, rbuf); if (t == 0) atomicAdd(&acc[23], r);
        r = blockReduceSum(p2, rbuf); if (t == 0) atomicAdd(&acc[24], r);
        r = blockReduceSum(g,  rbuf); if (t == 0) atomicAdd(&acc[25], r);
    }
}

// ---------------- K3: finalize + tr losses + combine (49 blocks) ------------
// Blocks 0-47: feature-cosine finalize (as R7). Block 48: tr losses.
// Last block to arrive (device-scope atomic counter) computes out[0].
// All intra-kernel cross-block values flow through device-scope atomics
// (atomicAdd to write, atomicAdd(p, 0.0f) to read) -> XCD-coherence safe.
__global__ void final_kernel(const float* __restrict__ pose,
                             const float* __restrict__ t1,
                             const float* __restrict__ t2,
                             float* __restrict__ ws,
                             float* __restrict__ out) {
    const int blk = blockIdx.x;
    const int t   = threadIdx.x;
    __shared__ float rbuf[16];

    if (blk < 48) {
        const int pr = blk >> 4;
        const int b  = blk & 15;
        const float4* PD = (const float4*)(ws + PACC_OFF + (size_t)((pr*16+b)*3 + 0) * 4096);
        const float4* PA = (const float4*)(ws + PACC_OFF + (size_t)((pr*16+b)*3 + 1) * 4096);
        const float4* PB = (const float4*)(ws + PACC_OFF + (size_t)((pr*16+b)*3 + 2) * 4096);
        const float cb    = ws[b];
        const float denom = fmaxf(cb, 1.0f);
        const int   cbi   = (int)cb;

        float v = 0.0f;
        #pragma unroll
        for (int it = 0; it < 4; it++) {
            int n4 = t + it * 256;
            float4 d = PD[n4], sa = PA[n4], sb = PB[n4];
            #pragma unroll
            for (int comp = 0; comp < 4; comp++) {
                float c = 1.0f - getc(d, comp) /
                          fmaxf(sqrtf(getc(sa, comp)) * sqrtf(getc(sb, comp)), EPSF);
                int n = n4 * 4 + comp;
                if (pr == 2)      v += c;
                else if (n < cbi) v += c / denom;
            }
        }
        float r = blockReduceSum(v, rbuf);
        if (t == 0) atomicAdd(&ws[18 + pr], r);
    } else {
        // tr losses on wave 0
        float dt1 = 0, dt2 = 0, r1 = 0, r2 = 0;
        if (t < 8) {
            float ap = acosf(fminf(fmaxf(pose[t*16], -1.0f), 1.0f));
            float a1 = acosf(fminf(fmaxf(t1[t*16],   -1.0f), 1.0f));
            float a2 = acosf(fminf(fmaxf(t2[t*16],   -1.0f), 1.0f));
            r1 = fabsf(a1 - ap);
            r2 = fabsf(a2 - ap);
            float s1 = 0, s2 = 0;
            #pragma unroll
            for (int r = 0; r < 3; r++) {
                float pv = pose[t*16 + r*4 + 3];
                float d1 = t1[t*16 + r*4 + 3] - pv;
                float d2 = t2[t*16 + r*4 + 3] - pv;
                s1 += d1 * d1;
                s2 += d2 * d2;
            }
            dt1 = sqrtf(s1);
            dt2 = sqrtf(s2);
        }
        if (t < 64) {
            #pragma unroll
            for (int o = 4; o > 0; o >>= 1) {
                dt1 += __shfl_down(dt1, o, 64);
                dt2 += __shfl_down(dt2, o, 64);
                r1  += __shfl_down(r1,  o, 64);
                r2  += __shfl_down(r2,  o, 64);
            }
        }
        if (t == 0) {
            atomicAdd(&ws[28], dt1);   // slots zeroed by memset -> add == store
            atomicAdd(&ws[29], dt2);
            atomicAdd(&ws[30], r1);
            atomicAdd(&ws[31], r2);
        }
        __syncthreads();
    }

    // arrival; last of the 49 blocks combines
    if (t == 0) {
        __threadfence();
        unsigned old = atomicAdd((unsigned int*)(ws + 27), 1u);
        if (old == 48u) {
            float dt1 = atomicAdd(&ws[28], 0.0f);
            float dt2 = atomicAdd(&ws[29], 0.0f);
            float r1  = atomicAdd(&ws[30], 0.0f);
            float r2  = atomicAdd(&ws[31], 0.0f);
            float gb  = atomicAdd(&ws[18], 0.0f);
            float gi  = atomicAdd(&ws[19], 0.0f);
            float gpa = atomicAdd(&ws[20], 0.0f);

            float l_tra1 = dt1 / 8.0f;
            float l_tra2 = dt2 / 8.0f;
            float l_rot1 = (r1 / 8.0f) / 3.1415f * 180.0f;
            float l_rot2 = (r2 / 8.0f) / 3.1415f * 180.0f;
            float cnt = (fminf(l_rot1, l_rot2) > 0.0f) ? 2.0f : 1.0f;

            float l_score = ws[16] / fmaxf(ws[17], 1.0f);   // mega-written (kernel boundary)
            float l_match = (ws[21] + ws[22]) / 32768.0f / cnt;
            float l_pose  = (ws[23] + ws[24]) / 98304.0f / cnt;
            float l_tra   = (l_tra1 + l_tra2) / cnt;
            float l_rot   = (l_rot1 + l_rot2) / cnt;
            float l_gb    = gb  / 16.0f;
            float l_gi    = gi  / 16.0f;
            float l_gpa   = gpa / 65536.0f;
            float l_gpo   = ws[25] / 131072.0f;

            out[0] = l_pose + l_score + l_match + l_tra + l_rot
                   + l_gb + l_gi + l_gpa + l_gpo;
        }
    }
}

extern "C" void kernel_launch(void* const* d_in, const int* in_sizes, int n_in,
                              void* d_out, int out_size, void* d_ws, size_t ws_size,
                              hipStream_t stream) {
    const float* score_bev   = (const float*)d_in[0];
    const float* label_score = (const float*)d_in[1];
    const float* key_points  = (const float*)d_in[2];
    const float* pose        = (const float*)d_in[3];
    // d_in[4] = batch_size (scalar, fixed = 16)
    const float* t_orig      = (const float*)d_in[5];
    const float* proj_orig   = (const float*)d_in[6];
    const float* t_fus       = (const float*)d_in[7];
    const float* proj_fus    = (const float*)d_in[8];
    const float* f_pt        = (const float*)d_in[9];
    const float* f_pt_g      = (const float*)d_in[10];
    const float* f_pl        = (const float*)d_in[11];
    const float* f_pl_g      = (const float*)d_in[12];
    const float* f_kpt       = (const float*)d_in[13];
    const float* f_kpt_g     = (const float*)d_in[14];
    const float* relation    = (const float*)d_in[15];
    const float* kgen        = (const float*)d_in[16];

    float* ws  = (float*)d_ws;
    float* out = (float*)d_out;

    hipMemsetAsync(d_ws, 0, (PACC_OFF + PACC_FLTS) * sizeof(float), stream);

    cnt_kernel<<<256, 256, 0, stream>>>(relation, ws);
    mega_kernel<<<MEGA_BLOCKS, 256, 0, stream>>>(
        f_pt, f_pt_g, f_pl, f_pl_g, f_kpt, f_kpt_g,
        score_bev, label_score,
        key_points, pose, t_orig, proj_orig, t_fus, proj_fus, kgen, ws);
    final_kernel<<<49, 256, 0, stream>>>(pose, t_orig, t_fus, ws, out);
}